// Round 5
// baseline (216.516 us; speedup 1.0000x reference)
//
#include <hip/hip_runtime.h>
#include <math.h>

// N=2, K=20 -> 40 images; C=64 channels; 16x16 images (256 px).
#define NIMG 40
#define PXI  256
#define CH   64
#define SB_ELEM (NIMG * PXI * CH)   // 655360 elems per activation tensor

typedef __bf16 bf16x8 __attribute__((ext_vector_type(8)));
typedef float  f32x4  __attribute__((ext_vector_type(4)));

static __device__ __forceinline__ unsigned short f2bf(float f) {
    unsigned u = __builtin_bit_cast(unsigned, f);
    u += 0x7fffu + ((u >> 16) & 1u);          // RNE
    return (unsigned short)(u >> 16);
}
static __device__ __forceinline__ unsigned pk2(float a, float b) {
    return (unsigned)f2bf(a) | ((unsigned)f2bf(b) << 16);
}
static __device__ __forceinline__ float bfu2f(unsigned hs) {  // bf16 bits in low 16
    unsigned u = (hs & 0xffffu) << 16;
    return __builtin_bit_cast(float, u);
}

// ---------------------------------------------------------------------------
// Single-source conv core (stage-1/2 convs, unchanged from R4): one wave does
// rows {y0,y0+1} x 4 oc-tiles from swizzled LDS Z and Wt bf16 [9][64oc][64ci].
// LDS 16B-slot index = pix*8 + (g ^ (pix&7)), g = ci/8.  (T2 swizzle)
// ---------------------------------------------------------------------------
static __device__ __forceinline__ void conv_tiles2(const uint4* __restrict__ ldsZ,
                                                   const uint4* __restrict__ Wt,
                                                   int y0, int lane, f32x4 acc[2][4])
{
    const int l15 = lane & 15;
    const int l4  = lane >> 4;
#pragma unroll
    for (int khalf = 0; khalf < 2; ++khalf) {
        const int g = khalf * 4 + l4;
#pragma unroll
        for (int kk = 0; kk < 9; ++kk) {
            const int ky = kk / 3 - 1;
            const int kx = kk % 3 - 1;
            bf16x8 bfrag[4];
#pragma unroll
            for (int oct = 0; oct < 4; ++oct)
                bfrag[oct] = __builtin_bit_cast(bf16x8, Wt[(kk * 64 + oct * 16 + l15) * 8 + g]);
#pragma unroll
            for (int r = 0; r < 2; ++r) {
                const int yy = y0 + r + ky;
                const int xx = l15 + kx;
                const bool inb = ((unsigned)yy < 16u) && ((unsigned)xx < 16u);
                const int pix = inb ? (yy * 16 + xx) : 0;
                uint4 av = ldsZ[pix * 8 + (g ^ (pix & 7))];
                if (!inb) { av.x = 0u; av.y = 0u; av.z = 0u; av.w = 0u; }
                bf16x8 afrag = __builtin_bit_cast(bf16x8, av);
#pragma unroll
                for (int oct = 0; oct < 4; ++oct)
                    acc[r][oct] = __builtin_amdgcn_mfma_f32_16x16x32_bf16(
                        afrag, bfrag[oct], acc[r][oct], 0, 0, 0);
            }
        }
    }
}

// ---------------------------------------------------------------------------
// Generic MFMA conv: X bf16 [img][256][64] -> out bf16 [img][256][64]
// ---------------------------------------------------------------------------
struct ConvDesc {
    const uint4* X;
    const uint4* W;
    const float* bias;      // nullptr -> no bias
    unsigned short* out;
    int relu;
};
struct ConvBatch { ConvDesc d[6]; };

__global__ __launch_bounds__(512)
void conv_mfma_k(ConvBatch cb)
{
    __shared__ uint4 ldsZ[2048];
    const ConvDesc d = cb.d[blockIdx.y];
    const int img = blockIdx.x;
    const int tid = threadIdx.x;

    const uint4* Xi = d.X + img * 2048;
#pragma unroll
    for (int i = 0; i < 4; ++i) {
        int u = i * 512 + tid;
        int px = u >> 3, g = u & 7;
        ldsZ[px * 8 + (g ^ (px & 7))] = Xi[u];
    }
    __syncthreads();

    const int lane = tid & 63, wv = tid >> 6;
    const int l15 = lane & 15, l4 = lane >> 4;
    f32x4 zz = {0.f, 0.f, 0.f, 0.f};
    f32x4 acc[2][4];
#pragma unroll
    for (int r = 0; r < 2; ++r)
#pragma unroll
        for (int o = 0; o < 4; ++o) acc[r][o] = zz;

    conv_tiles2(ldsZ, d.W, wv * 2, lane, acc);

#pragma unroll
    for (int oct = 0; oct < 4; ++oct) {
        const int oc = oct * 16 + l15;
        const float b = d.bias ? d.bias[oc] : 0.f;
#pragma unroll
        for (int r = 0; r < 2; ++r)
#pragma unroll
            for (int e = 0; e < 4; ++e) {
                float v = acc[r][oct][e] + b;
                if (d.relu) v = fmaxf(v, 0.f);
                const int px = (wv * 2 + r) * 16 + l4 * 4 + e;
                d.out[(img * PXI + px) * CH + oc] = f2bf(v);
            }
    }
}

// ---------------------------------------------------------------------------
// Pair kernel v5: weights VGPR-resident, wave = one 16-oc group.
// Block = (imgb, s): 2 sources a = 2s, 2s+1 (diagonal included; reference
// sums ALL j then divides by K-1). 256 threads = 4 waves (wave id = oct).
// Per conv pass: 18 resident weight uint4s, 96 LDS reads, 276 MFMAs
// (row-reuse: input row r feeds output rows r-1,r,r+1).
// ---------------------------------------------------------------------------
static __device__ __forceinline__ uint4 relu_add4(uint4 a, uint4 b) {
    uint4 o;
    unsigned* ap = &a.x; unsigned* bp = &b.x; unsigned* op = &o.x;
#pragma unroll
    for (int w = 0; w < 4; ++w) {
        float a0 = __builtin_bit_cast(float, ap[w] << 16);
        float a1 = __builtin_bit_cast(float, ap[w] & 0xffff0000u);
        float b0 = __builtin_bit_cast(float, bp[w] << 16);
        float b1 = __builtin_bit_cast(float, bp[w] & 0xffff0000u);
        op[w] = pk2(fmaxf(a0 + b0, 0.f), fmaxf(a1 + b1, 0.f));
    }
    return o;
}

static __device__ __forceinline__ void build_z256(uint4* __restrict__ Z,
                                                  const uint4* __restrict__ A,
                                                  const uint4* __restrict__ B, int tid)
{
#pragma unroll
    for (int i = 0; i < 8; ++i) {
        int u = i * 256 + tid;
        int slot = (u >> 3) * 8 + ((u & 7) ^ ((u >> 3) & 7));
        Z[slot] = relu_add4(A[u], B[u]);
    }
}

static __device__ __forceinline__ void load_w18(uint4 wr[2][9], const uint4* __restrict__ Wt,
                                                int oct, int l15, int l4)
{
#pragma unroll
    for (int kh = 0; kh < 2; ++kh)
#pragma unroll
        for (int kk = 0; kk < 9; ++kk)
            wr[kh][kk] = Wt[(kk * 64 + oct * 16 + l15) * 8 + kh * 4 + l4];
}

static __device__ __forceinline__ void conv16(const char* __restrict__ zb,
                                              const uint4 wr[2][9],
                                              const unsigned base[2][3],
                                              const unsigned step[3],
                                              f32x4 acc[16])
{
#pragma unroll
    for (int r = 0; r < 16; ++r) {
        uint4 a[2][3];
#pragma unroll
        for (int kh = 0; kh < 2; ++kh)
#pragma unroll
            for (int kx = 0; kx < 3; ++kx)
                a[kh][kx] = *(const uint4*)(zb + (base[kh][kx] + (unsigned)r * step[kx]));
#pragma unroll
        for (int kx = 0; kx < 3; ++kx)
#pragma unroll
            for (int kh = 0; kh < 2; ++kh)
#pragma unroll
                for (int ky = 0; ky < 3; ++ky) {
                    const int orow = r + 1 - ky;
                    if (orow < 0 || orow > 15) continue;
                    acc[orow] = __builtin_amdgcn_mfma_f32_16x16x32_bf16(
                        __builtin_bit_cast(bf16x8, a[kh][kx]),
                        __builtin_bit_cast(bf16x8, wr[kh][ky * 3 + kx]),
                        acc[orow], 0, 0, 0);
                }
    }
}

__global__ __launch_bounds__(256, 2)
void pair_mfma_k(const uint4* __restrict__ Abf, const uint4* __restrict__ Bbf,
                 const uint4* __restrict__ Agbf, const uint4* __restrict__ Bgbf,
                 const uint4* __restrict__ W2, const uint4* __restrict__ Wg2,
                 const float* __restrict__ b2, const float* __restrict__ bg2,
                 unsigned short* __restrict__ partials)
{
    __shared__ uint4 Z[2056];               // 2048 data slots + zero slot at 2048
    const char* zb = (const char*)Z;
    const int bi   = blockIdx.x;            // 0..399
    const int imgb = bi / 10;
    const int s    = bi % 10;
    const int n    = imgb / 20;
    const int tid  = threadIdx.x;
    const int lane = tid & 63;
    const int oct  = tid >> 6;              // wave id = oc group
    const int l15 = lane & 15, l4 = lane >> 4;

    const float bm = b2[oct * 16 + l15];
    const float bg = bg2[oct * 16 + l15];

    // Per-lane LDS read addressing: addr = base[kh][kx] + r*step[kx].
    // Invalid x (border) lanes: base = zero slot, step = 0.
    unsigned base[2][3], step[3];
#pragma unroll
    for (int kx = 0; kx < 3; ++kx) {
        const int xi = l15 + kx - 1;
        const bool valid = (unsigned)xi < 16u;
        step[kx] = valid ? 2048u : 0u;
#pragma unroll
        for (int kh = 0; kh < 2; ++kh) {
            const int g = kh * 4 + l4;
            base[kh][kx] = valid ? (unsigned)(xi * 128 + ((g ^ (xi & 7)) << 4))
                                 : 32768u;
        }
    }

    unsigned run[16][2];
#pragma unroll
    for (int r = 0; r < 16; ++r) { run[r][0] = 0u; run[r][1] = 0u; }

    const f32x4 zz = {0.f, 0.f, 0.f, 0.f};

#pragma unroll 1
    for (int ia = 0; ia < 2; ++ia) {
        const int imga = n * 20 + s * 2 + ia;

        // ---- msg branch ----
        build_z256(Z, Abf + imgb * 2048, Bbf + imga * 2048, tid);
        if (tid == 0) { uint4 z4 = {0u, 0u, 0u, 0u}; Z[2048] = z4; }
        __syncthreads();

        uint4 wr[2][9];
        load_w18(wr, W2, oct, l15, l4);
        f32x4 acc[16];
#pragma unroll
        for (int r = 0; r < 16; ++r) acc[r] = zz;
        conv16(zb, wr, base, step, acc);

        unsigned stash[16][2];
#pragma unroll
        for (int r = 0; r < 16; ++r) {
            stash[r][0] = pk2(acc[r][0] + bm, acc[r][1] + bm);
            stash[r][1] = pk2(acc[r][2] + bm, acc[r][3] + bm);
        }
        __syncthreads();

        // ---- gate branch ----
        build_z256(Z, Agbf + imgb * 2048, Bgbf + imga * 2048, tid);
        __syncthreads();

        load_w18(wr, Wg2, oct, l15, l4);
#pragma unroll
        for (int r = 0; r < 16; ++r) acc[r] = zz;
        conv16(zb, wr, base, step, acc);

        // ---- combine into running bf16 sum ----
#pragma unroll
        for (int r = 0; r < 16; ++r) {
            float o[4];
#pragma unroll
            for (int e = 0; e < 4; ++e) {
                const float gt = acc[r][e] + bg;
                const float m  = bfu2f(stash[r][e >> 1] >> ((e & 1) * 16));
                o[e] = m * (1.f / (1.f + __expf(-gt)));
            }
            run[r][0] = pk2(bfu2f(run[r][0]) + o[0], bfu2f(run[r][0] >> 16) + o[1]);
            run[r][1] = pk2(bfu2f(run[r][1]) + o[2], bfu2f(run[r][1] >> 16) + o[3]);
        }
        __syncthreads();   // all waves done reading Z before next build
    }

    // ---- store: partials[s][img][oc][px], 8B per lane per row ----
    const int pbase = (s * NIMG + imgb) * (PXI * CH) + (oct * 16 + l15) * PXI;
#pragma unroll
    for (int r = 0; r < 16; ++r) {
        uint2 pkd; pkd.x = run[r][0]; pkd.y = run[r][1];
        *(uint2*)&partials[pbase + r * 16 + l4 * 4] = pkd;
    }
}

// ---------------------------------------------------------------------------
// Merged prep: weight repack (blocks 0..1583) + X padding (blocks 1584..4143)
// ---------------------------------------------------------------------------
struct WPrep { const float* src; unsigned short* dst; int cin_src; int cioff; int nvalid; };
struct WPrepBatch { WPrep w[11]; };

__global__ __launch_bounds__(256)
void prep_k(WPrepBatch wb, const float* __restrict__ x, const float* __restrict__ t,
            unsigned short* __restrict__ Xpad)
{
    const int bx = blockIdx.x;
    if (bx < 1584) {
        const WPrep p = wb.w[bx / 144];
        const int idx = (bx % 144) * 256 + threadIdx.x;   // 0..36863
        const int kk = idx >> 12;
        const int oc = (idx >> 6) & 63;
        const int ci = idx & 63;
        float v = 0.f;
        if (ci < p.nvalid)
            v = p.src[(oc * p.cin_src + p.cioff + ci) * 9 + kk];
        p.dst[idx] = f2bf(v);
    } else {
        const int idx = (bx - 1584) * 256 + threadIdx.x;  // 0..655359
        const int img = idx >> 14;
        const int px  = (idx >> 6) & 255;
        const int ch  = idx & 63;
        float v;
        if (ch == 0)       v = t[0];
        else if (ch <= 32) v = x[((img * 32) + (ch - 1)) * PXI + px];
        else               v = 0.f;
        Xpad[idx] = f2bf(v);
    }
}

// ---------------------------------------------------------------------------
// Final: out[img][oc][px] = u*sigmoid(ug) + (sum_s partials[s])/19.
// u/ug are [px][oc] (transposed via LDS); partials already [oc][px].
// ---------------------------------------------------------------------------
__global__ __launch_bounds__(512)
void final_k(const unsigned short* __restrict__ u_lin,
             const unsigned short* __restrict__ ug_lin,
             const unsigned short* __restrict__ P,
             float* __restrict__ out)
{
    __shared__ float buf[PXI * 65];
    const int img = blockIdx.x;
    const int tid = threadIdx.x;

#pragma unroll
    for (int i = 0; i < 32; ++i) {
        const int idx = i * 512 + tid;          // [px][oc], oc innermost
        const int px = idx >> 6, oc = idx & 63;
        const float u = bfu2f(u_lin[img * (PXI * CH) + idx]);
        const float g = bfu2f(ug_lin[img * (PXI * CH) + idx]);
        buf[px * 65 + oc] = u * (1.f / (1.f + __expf(-g)));
    }
    __syncthreads();
#pragma unroll
    for (int i = 0; i < 32; ++i) {
        const int j = i * 512 + tid;            // [oc][px], px innermost
        const int oc = j >> 8, px = j & 255;
        float ssum = 0.f;
#pragma unroll
        for (int sl = 0; sl < 10; ++sl)
            ssum += bfu2f(P[(sl * NIMG + img) * (PXI * CH) + j]);
        out[img * (PXI * CH) + j] = buf[px * 65 + oc] + ssum * (1.f / 19.f);
    }
}

// ---------------------------------------------------------------------------
extern "C" void kernel_launch(void* const* d_in, const int* in_sizes, int n_in,
                              void* d_out, int out_size, void* d_ws, size_t ws_size,
                              hipStream_t stream)
{
    const float* t     = (const float*)d_in[0];
    const float* x     = (const float*)d_in[1];
    const float* w_map = (const float*)d_in[2];
    const float* b_map = (const float*)d_in[3];
    const float* w_u1  = (const float*)d_in[4];
    const float* b_u1  = (const float*)d_in[5];
    const float* w_u2  = (const float*)d_in[6];
    const float* b_u2  = (const float*)d_in[7];
    const float* w_ug1 = (const float*)d_in[8];
    const float* b_ug1 = (const float*)d_in[9];
    const float* w_ug2 = (const float*)d_in[10];
    const float* b_ug2 = (const float*)d_in[11];
    const float* w_b1  = (const float*)d_in[12];
    const float* b_b1  = (const float*)d_in[13];
    const float* w_b2  = (const float*)d_in[14];
    const float* b_b2  = (const float*)d_in[15];
    const float* w_bg1 = (const float*)d_in[16];
    const float* b_bg1 = (const float*)d_in[17];
    const float* w_bg2 = (const float*)d_in[18];
    const float* b_bg2 = (const float*)d_in[19];

    float* out = (float*)d_out;
    char* ws = (char*)d_ws;

    const size_t ABYTES = (size_t)SB_ELEM * 2;      // 1,310,720 B per bf16 tensor

    // Partials (10 bf16 slabs) overlay slabs 0..9; Xpad/h/p1/pg1 live in the
    // first 4 and are dead before pair_mfma_k runs (stream order).
    unsigned short* partials = (unsigned short*)(ws);
    unsigned short* Xpad   = (unsigned short*)(ws + 0 * ABYTES);
    unsigned short* h      = (unsigned short*)(ws + 1 * ABYTES);
    unsigned short* p1     = (unsigned short*)(ws + 2 * ABYTES);
    unsigned short* pg1    = (unsigned short*)(ws + 3 * ABYTES);
    unsigned short* u_lin  = (unsigned short*)(ws + 10 * ABYTES);
    unsigned short* ug_lin = (unsigned short*)(ws + 11 * ABYTES);
    unsigned short* Abuf   = (unsigned short*)(ws + 12 * ABYTES);
    unsigned short* Bbuf   = (unsigned short*)(ws + 13 * ABYTES);
    unsigned short* Agbuf  = (unsigned short*)(ws + 14 * ABYTES);
    unsigned short* Bgbuf  = (unsigned short*)(ws + 15 * ABYTES);
    char* wbase = ws + 16 * ABYTES;                 // ~21 MB
    const size_t WBYTES = 9 * 64 * 64 * 2;          // 73,728 B per weight tensor
    unsigned short* Wmap  = (unsigned short*)(wbase + 0 * WBYTES);
    unsigned short* Wu1   = (unsigned short*)(wbase + 1 * WBYTES);
    unsigned short* Wu2   = (unsigned short*)(wbase + 2 * WBYTES);
    unsigned short* Wug1  = (unsigned short*)(wbase + 3 * WBYTES);
    unsigned short* Wug2  = (unsigned short*)(wbase + 4 * WBYTES);
    unsigned short* Wb1a  = (unsigned short*)(wbase + 5 * WBYTES);
    unsigned short* Wb1b  = (unsigned short*)(wbase + 6 * WBYTES);
    unsigned short* Wbg1a = (unsigned short*)(wbase + 7 * WBYTES);
    unsigned short* Wbg1b = (unsigned short*)(wbase + 8 * WBYTES);
    unsigned short* Wb2   = (unsigned short*)(wbase + 9 * WBYTES);
    unsigned short* Wbg2  = (unsigned short*)(wbase + 10 * WBYTES);

    // --- prep: weights repack + Xpad build (one launch) ---
    WPrepBatch wb;
    wb.w[0]  = { w_map, Wmap,  33,  0, 33 };
    wb.w[1]  = { w_u1,  Wu1,   64,  0, 64 };
    wb.w[2]  = { w_u2,  Wu2,   64,  0, 64 };
    wb.w[3]  = { w_ug1, Wug1,  64,  0, 64 };
    wb.w[4]  = { w_ug2, Wug2,  64,  0, 64 };
    wb.w[5]  = { w_b1,  Wb1a, 128,  0, 64 };
    wb.w[6]  = { w_b1,  Wb1b, 128, 64, 64 };
    wb.w[7]  = { w_bg1, Wbg1a,128,  0, 64 };
    wb.w[8]  = { w_bg1, Wbg1b,128, 64, 64 };
    wb.w[9]  = { w_b2,  Wb2,   64,  0, 64 };
    wb.w[10] = { w_bg2, Wbg2,  64,  0, 64 };
    prep_k<<<dim3(1584 + 2560), dim3(256), 0, stream>>>(wb, x, t, Xpad);

    // --- map conv: h = conv(Xpad, w_map) + b_map ---
    ConvBatch cm{};
    cm.d[0] = { (const uint4*)Xpad, (const uint4*)Wmap, b_map, h, 0 };
    for (int i = 1; i < 6; ++i) cm.d[i] = cm.d[0];
    conv_mfma_k<<<dim3(NIMG, 1), dim3(512), 0, stream>>>(cm);

    // --- stage 1: six convs from h ---
    ConvBatch c1{};
    c1.d[0] = { (const uint4*)h, (const uint4*)Wu1,   b_u1,  p1,    1 };
    c1.d[1] = { (const uint4*)h, (const uint4*)Wug1,  b_ug1, pg1,   1 };
    c1.d[2] = { (const uint4*)h, (const uint4*)Wb1a,  b_b1,  Abuf,  0 };
    c1.d[3] = { (const uint4*)h, (const uint4*)Wb1b,  nullptr, Bbuf, 0 };
    c1.d[4] = { (const uint4*)h, (const uint4*)Wbg1a, b_bg1, Agbuf, 0 };
    c1.d[5] = { (const uint4*)h, (const uint4*)Wbg1b, nullptr, Bgbuf, 0 };
    conv_mfma_k<<<dim3(NIMG, 6), dim3(512), 0, stream>>>(c1);

    // --- stage 2: u_lin, ug_lin ---
    ConvBatch c2{};
    c2.d[0] = { (const uint4*)p1,  (const uint4*)Wu2,  b_u2,  u_lin,  0 };
    c2.d[1] = { (const uint4*)pg1, (const uint4*)Wug2, b_ug2, ug_lin, 0 };
    for (int i = 2; i < 6; ++i) c2.d[i] = c2.d[0];
    conv_mfma_k<<<dim3(NIMG, 2), dim3(512), 0, stream>>>(c2);

    // --- pairwise messages -> bf16 partial slabs (weights VGPR-resident) ---
    pair_mfma_k<<<dim3(400), dim3(256), 0, stream>>>(
        (const uint4*)Abuf, (const uint4*)Bbuf, (const uint4*)Agbuf, (const uint4*)Bgbuf,
        (const uint4*)Wb2, (const uint4*)Wbg2, b_b2, b_bg2, partials);

    // --- final combine ---
    final_k<<<dim3(NIMG), dim3(512), 0, stream>>>(u_lin, ug_lin, partials, out);
}

// Round 6
// 210.525 us; speedup vs baseline: 1.0285x; 1.0285x over previous
//
#include <hip/hip_runtime.h>
#include <math.h>

// N=2, K=20 -> 40 images; C=64 channels; 16x16 images (256 px).
#define NIMG 40
#define PXI  256
#define CH   64
#define SB_ELEM (NIMG * PXI * CH)   // 655360 elems per activation tensor
#define ZEROOFF 32768u              // byte offset of the 16B zero slot in LDS Z

typedef __bf16 bf16x8 __attribute__((ext_vector_type(8)));
typedef float  f32x4  __attribute__((ext_vector_type(4)));

static __device__ __forceinline__ unsigned short f2bf(float f) {
    unsigned u = __builtin_bit_cast(unsigned, f);
    u += 0x7fffu + ((u >> 16) & 1u);          // RNE
    return (unsigned short)(u >> 16);
}
static __device__ __forceinline__ unsigned pk2(float a, float b) {
    return (unsigned)f2bf(a) | ((unsigned)f2bf(b) << 16);
}
static __device__ __forceinline__ float bfu2f(unsigned hs) {  // bf16 bits in low 16
    unsigned u = (hs & 0xffffu) << 16;
    return __builtin_bit_cast(float, u);
}

// ---------------------------------------------------------------------------
// Shared conv core. Z in LDS, swizzled: pixel pix, ci-group g (16B) at byte
//   pix*128 + ((g ^ (pix&7))<<4);  zero slot at ZEROOFF.
// Weights (repacked, coalesced): uint4 index = ((kk*2+kh)*4 + oct)*64 + lane.
// Wave computes R rows x O oc-tiles starting at row r0, octs octg0..octg0+O-1.
// Per (kx,kh): load 3*O weight frags (contiguous 1KB each), then d-loop with
// one A-read per input row feeding up to 3 output rows (row-reuse).
// ---------------------------------------------------------------------------
template<int R, int O>
static __device__ __forceinline__ void conv_core(const char* __restrict__ zb,
                                                 const uint4* __restrict__ Wt,
                                                 int octg0, int r0, int lane,
                                                 const unsigned base[2][3],
                                                 const unsigned step[3],
                                                 f32x4 (&acc)[R][O])
{
#pragma unroll
    for (int kx = 0; kx < 3; ++kx)
#pragma unroll
        for (int kh = 0; kh < 2; ++kh) {
            uint4 w[3][O];
#pragma unroll
            for (int ky = 0; ky < 3; ++ky)
#pragma unroll
                for (int o = 0; o < O; ++o)
                    w[ky][o] = Wt[(((ky * 3 + kx) * 2 + kh) * 4 + octg0 + o) * 64 + lane];
#pragma unroll
            for (int dd = 0; dd < R + 2; ++dd) {
                const int ri = r0 + dd - 1;          // input row (wave-uniform)
                if (ri >= 0 && ri < 16) {
                    uint4 a = *(const uint4*)(zb + (base[kh][kx] + (unsigned)ri * step[kx]));
                    bf16x8 af = __builtin_bit_cast(bf16x8, a);
#pragma unroll
                    for (int ky = 0; ky < 3; ++ky) {
                        const int orow = dd - ky;
                        if (orow < 0 || orow >= R) continue;
#pragma unroll
                        for (int o = 0; o < O; ++o)
                            acc[orow][o] = __builtin_amdgcn_mfma_f32_16x16x32_bf16(
                                af, __builtin_bit_cast(bf16x8, w[ky][o]), acc[orow][o], 0, 0, 0);
                    }
                }
            }
        }
}

static __device__ __forceinline__ void make_base(unsigned base[2][3], unsigned step[3],
                                                 int l15, int l4)
{
#pragma unroll
    for (int kx = 0; kx < 3; ++kx) {
        const int xi = l15 + kx - 1;
        const bool valid = (unsigned)xi < 16u;
        step[kx] = valid ? 2048u : 0u;
#pragma unroll
        for (int kh = 0; kh < 2; ++kh) {
            const int g = kh * 4 + l4;
            base[kh][kx] = valid ? (unsigned)(xi * 128 + (((g ^ (xi & 7))) << 4))
                                 : ZEROOFF;
        }
    }
}

// ---------------------------------------------------------------------------
// Stage convs: X bf16 [img][256][64] -> out bf16 [img][256][64].
// 256 thr = 4 waves (rg = wv&1: 4 rows, op = wv>>1: 2 octs), grid (img, desc, half).
// ---------------------------------------------------------------------------
struct ConvDesc {
    const uint4* X;
    const uint4* W;
    const float* bias;      // nullptr -> no bias
    unsigned short* out;
    int relu;
};
struct ConvBatch { ConvDesc d[6]; };

__global__ __launch_bounds__(256)
void conv_mfma_k(ConvBatch cb)
{
    __shared__ uint4 Z[2049];
    const ConvDesc d = cb.d[blockIdx.y];
    const int img = blockIdx.x;
    const int tid = threadIdx.x;

    const uint4* Xi = d.X + img * 2048;
#pragma unroll
    for (int i = 0; i < 8; ++i) {
        int u = i * 256 + tid;
        int px = u >> 3, g = u & 7;
        Z[px * 8 + (g ^ (px & 7))] = Xi[u];
    }
    if (tid == 0) { uint4 z4 = {0u, 0u, 0u, 0u}; Z[2048] = z4; }
    __syncthreads();

    const int lane = tid & 63, wv = tid >> 6;
    const int l15 = lane & 15, l4 = lane >> 4;
    const int rg = wv & 1, op = wv >> 1;
    const int r0 = blockIdx.z * 8 + rg * 4;

    unsigned base[2][3], step[3];
    make_base(base, step, l15, l4);

    f32x4 acc[4][2];
    const f32x4 zz = {0.f, 0.f, 0.f, 0.f};
#pragma unroll
    for (int r = 0; r < 4; ++r)
#pragma unroll
        for (int o = 0; o < 2; ++o) acc[r][o] = zz;

    conv_core<4, 2>((const char*)Z, d.W, op * 2, r0, lane, base, step, acc);

#pragma unroll
    for (int o = 0; o < 2; ++o) {
        const int oc = (op * 2 + o) * 16 + l15;
        const float b = d.bias ? d.bias[oc] : 0.f;
#pragma unroll
        for (int r = 0; r < 4; ++r)
#pragma unroll
            for (int e = 0; e < 4; ++e) {
                float v = acc[r][o][e] + b;
                if (d.relu) v = fmaxf(v, 0.f);
                const int px = (r0 + r) * 16 + l4 * 4 + e;
                d.out[(img * PXI + px) * CH + oc] = f2bf(v);
            }
    }
}

// ---------------------------------------------------------------------------
// Pair kernel: grid 400 (XCD-swizzled), 512 thr = 8 waves, Z single-source
// 32.8KB LDS. Block (imgb, s) loops ia over sources {2s, 2s+1}.
// Wave = 8 rows x 1 oct: acc 32 + stash 16 + run 16 + w 12 regs.
// ---------------------------------------------------------------------------
static __device__ __forceinline__ uint4 relu_add4(uint4 a, uint4 b) {
    uint4 o;
    unsigned* ap = &a.x; unsigned* bp = &b.x; unsigned* op2 = &o.x;
#pragma unroll
    for (int w = 0; w < 4; ++w) {
        float a0 = __builtin_bit_cast(float, ap[w] << 16);
        float a1 = __builtin_bit_cast(float, ap[w] & 0xffff0000u);
        float b0 = __builtin_bit_cast(float, bp[w] << 16);
        float b1 = __builtin_bit_cast(float, bp[w] & 0xffff0000u);
        op2[w] = pk2(fmaxf(a0 + b0, 0.f), fmaxf(a1 + b1, 0.f));
    }
    return o;
}

__global__ __launch_bounds__(512)
void pair_mfma_k(const uint4* __restrict__ Abf, const uint4* __restrict__ Bbf,
                 const uint4* __restrict__ Agbf, const uint4* __restrict__ Bgbf,
                 const uint4* __restrict__ W2, const uint4* __restrict__ Wg2,
                 const float* __restrict__ b2, const float* __restrict__ bg2,
                 unsigned short* __restrict__ partials)
{
    __shared__ uint4 Z[2049];
    const char* zb = (const char*)Z;
    // XCD-chunked bijective swizzle (400 % 8 == 0): XCD k -> imgb range [5k,5k+5)
    const int bi0 = blockIdx.x;
    const int bi  = (bi0 & 7) * 50 + (bi0 >> 3);
    const int imgb = bi / 10;
    const int s    = bi % 10;
    const int n    = imgb / 20;
    const int tid  = threadIdx.x;
    const int lane = tid & 63, wv = tid >> 6;
    const int l15 = lane & 15, l4 = lane >> 4;
    const int rg  = wv & 1;             // row half
    const int oct = wv >> 1;            // oc group 0..3
    const int r0  = rg * 8;

    const float bm = b2[oct * 16 + l15];
    const float bg = bg2[oct * 16 + l15];

    unsigned base[2][3], step[3];
    make_base(base, step, l15, l4);

    if (tid == 0) { uint4 z4 = {0u, 0u, 0u, 0u}; Z[2048] = z4; }

    unsigned run[8][2];
#pragma unroll
    for (int r = 0; r < 8; ++r) { run[r][0] = 0u; run[r][1] = 0u; }

    const f32x4 zz = {0.f, 0.f, 0.f, 0.f};
    const uint4* Ap  = Abf  + imgb * 2048;
    const uint4* Agp = Agbf + imgb * 2048;

#pragma unroll 1
    for (int ia = 0; ia < 2; ++ia) {
        const int imga = n * 20 + s * 2 + ia;
        const uint4* Bp  = Bbf  + imga * 2048;
        const uint4* Bgp = Bgbf + imga * 2048;

        // ---- msg: Z = relu(A[b] + B[a]) ----
#pragma unroll
        for (int i = 0; i < 4; ++i) {
            int u = i * 512 + tid;
            int px = u >> 3, g = u & 7;
            Z[px * 8 + (g ^ (px & 7))] = relu_add4(Ap[u], Bp[u]);
        }
        __syncthreads();

        f32x4 acc[8][1];
#pragma unroll
        for (int r = 0; r < 8; ++r) acc[r][0] = zz;
        conv_core<8, 1>(zb, W2, oct, r0, lane, base, step, acc);

        unsigned stash[8][2];
#pragma unroll
        for (int r = 0; r < 8; ++r) {
            stash[r][0] = pk2(acc[r][0][0] + bm, acc[r][0][1] + bm);
            stash[r][1] = pk2(acc[r][0][2] + bm, acc[r][0][3] + bm);
        }
        __syncthreads();   // all reads of Z done

        // ---- gate: Z = relu(Ag[b] + Bg[a]) ----
#pragma unroll
        for (int i = 0; i < 4; ++i) {
            int u = i * 512 + tid;
            int px = u >> 3, g = u & 7;
            Z[px * 8 + (g ^ (px & 7))] = relu_add4(Agp[u], Bgp[u]);
        }
        __syncthreads();

#pragma unroll
        for (int r = 0; r < 8; ++r) acc[r][0] = zz;
        conv_core<8, 1>(zb, Wg2, oct, r0, lane, base, step, acc);

#pragma unroll
        for (int r = 0; r < 8; ++r) {
            float o[4];
#pragma unroll
            for (int e = 0; e < 4; ++e) {
                const float gt = acc[r][0][e] + bg;
                const float m  = bfu2f(stash[r][e >> 1] >> ((e & 1) * 16));
                o[e] = m * (1.f / (1.f + __expf(-gt)));
            }
            run[r][0] = pk2(bfu2f(run[r][0]) + o[0], bfu2f(run[r][0] >> 16) + o[1]);
            run[r][1] = pk2(bfu2f(run[r][1]) + o[2], bfu2f(run[r][1] >> 16) + o[3]);
        }
        __syncthreads();   // protect Z before next ia's build
    }

    // ---- store: partials[s][img][oc][px] ----
    const int pbase = (s * NIMG + imgb) * (PXI * CH) + (oct * 16 + l15) * PXI;
#pragma unroll
    for (int r = 0; r < 8; ++r) {
        uint2 pkd; pkd.x = run[r][0]; pkd.y = run[r][1];
        *(uint2*)&partials[pbase + (r0 + r) * 16 + l4 * 4] = pkd;
    }
}

// ---------------------------------------------------------------------------
// Merged prep: weight repack (blocks 0..1583) + X padding (blocks 1584..4143)
// New weight layout (coalesced): uint4 index = ((kk*2+kh)*4 + oct)*64 + lane;
// element (lane,j): oc = oct*16 + (lane&15), ci = (kh*4 + (lane>>4))*8 + j.
// ---------------------------------------------------------------------------
struct WPrep { const float* src; unsigned short* dst; int cin_src; int cioff; int nvalid; };
struct WPrepBatch { WPrep w[11]; };

__global__ __launch_bounds__(256)
void prep_k(WPrepBatch wb, const float* __restrict__ x, const float* __restrict__ t,
            unsigned short* __restrict__ Xpad)
{
    const int bx = blockIdx.x;
    if (bx < 1584) {
        const WPrep p = wb.w[bx / 144];
        const int e = (bx % 144) * 256 + threadIdx.x;   // 0..36863
        const int j = e & 7;
        const int u4 = e >> 3;
        const int lane = u4 & 63;
        const int oct = (u4 >> 6) & 3;
        const int kh  = (u4 >> 8) & 1;
        const int kk  = u4 >> 9;
        const int oc  = oct * 16 + (lane & 15);
        const int ci  = (kh * 4 + (lane >> 4)) * 8 + j;
        float v = 0.f;
        if (ci < p.nvalid)
            v = p.src[(oc * p.cin_src + p.cioff + ci) * 9 + kk];
        p.dst[e] = f2bf(v);
    } else {
        const int idx = (bx - 1584) * 256 + threadIdx.x;  // 0..655359
        const int img = idx >> 14;
        const int px  = (idx >> 6) & 255;
        const int ch  = idx & 63;
        float v;
        if (ch == 0)       v = t[0];
        else if (ch <= 32) v = x[((img * 32) + (ch - 1)) * PXI + px];
        else               v = 0.f;
        Xpad[idx] = f2bf(v);
    }
}

// ---------------------------------------------------------------------------
// Final: out[img][oc][px] = u*sigmoid(ug) + (sum_s partials[s])/19.
// ---------------------------------------------------------------------------
__global__ __launch_bounds__(512)
void final_k(const unsigned short* __restrict__ u_lin,
             const unsigned short* __restrict__ ug_lin,
             const unsigned short* __restrict__ P,
             float* __restrict__ out)
{
    __shared__ float buf[PXI * 65];
    const int img = blockIdx.x;
    const int tid = threadIdx.x;

#pragma unroll
    for (int i = 0; i < 32; ++i) {
        const int idx = i * 512 + tid;          // [px][oc], oc innermost
        const int px = idx >> 6, oc = idx & 63;
        const float u = bfu2f(u_lin[img * (PXI * CH) + idx]);
        const float g = bfu2f(ug_lin[img * (PXI * CH) + idx]);
        buf[px * 65 + oc] = u * (1.f / (1.f + __expf(-g)));
    }
    __syncthreads();
#pragma unroll
    for (int i = 0; i < 32; ++i) {
        const int j = i * 512 + tid;            // [oc][px], px innermost
        const int oc = j >> 8, px = j & 255;
        float ssum = 0.f;
#pragma unroll
        for (int sl = 0; sl < 10; ++sl)
            ssum += bfu2f(P[(sl * NIMG + img) * (PXI * CH) + j]);
        out[img * (PXI * CH) + j] = buf[px * 65 + oc] + ssum * (1.f / 19.f);
    }
}

// ---------------------------------------------------------------------------
extern "C" void kernel_launch(void* const* d_in, const int* in_sizes, int n_in,
                              void* d_out, int out_size, void* d_ws, size_t ws_size,
                              hipStream_t stream)
{
    const float* t     = (const float*)d_in[0];
    const float* x     = (const float*)d_in[1];
    const float* w_map = (const float*)d_in[2];
    const float* b_map = (const float*)d_in[3];
    const float* w_u1  = (const float*)d_in[4];
    const float* b_u1  = (const float*)d_in[5];
    const float* w_u2  = (const float*)d_in[6];
    const float* b_u2  = (const float*)d_in[7];
    const float* w_ug1 = (const float*)d_in[8];
    const float* b_ug1 = (const float*)d_in[9];
    const float* w_ug2 = (const float*)d_in[10];
    const float* b_ug2 = (const float*)d_in[11];
    const float* w_b1  = (const float*)d_in[12];
    const float* b_b1  = (const float*)d_in[13];
    const float* w_b2  = (const float*)d_in[14];
    const float* b_b2  = (const float*)d_in[15];
    const float* w_bg1 = (const float*)d_in[16];
    const float* b_bg1 = (const float*)d_in[17];
    const float* w_bg2 = (const float*)d_in[18];
    const float* b_bg2 = (const float*)d_in[19];

    float* out = (float*)d_out;
    char* ws = (char*)d_ws;

    const size_t ABYTES = (size_t)SB_ELEM * 2;      // 1,310,720 B per bf16 tensor

    // Partials (10 bf16 slabs) overlay slabs 0..9; Xpad/h/p1/pg1 live in the
    // first 4 and are dead before pair_mfma_k runs (stream order).
    unsigned short* partials = (unsigned short*)(ws);
    unsigned short* Xpad   = (unsigned short*)(ws + 0 * ABYTES);
    unsigned short* h      = (unsigned short*)(ws + 1 * ABYTES);
    unsigned short* p1     = (unsigned short*)(ws + 2 * ABYTES);
    unsigned short* pg1    = (unsigned short*)(ws + 3 * ABYTES);
    unsigned short* u_lin  = (unsigned short*)(ws + 10 * ABYTES);
    unsigned short* ug_lin = (unsigned short*)(ws + 11 * ABYTES);
    unsigned short* Abuf   = (unsigned short*)(ws + 12 * ABYTES);
    unsigned short* Bbuf   = (unsigned short*)(ws + 13 * ABYTES);
    unsigned short* Agbuf  = (unsigned short*)(ws + 14 * ABYTES);
    unsigned short* Bgbuf  = (unsigned short*)(ws + 15 * ABYTES);
    char* wbase = ws + 16 * ABYTES;                 // ~21 MB
    const size_t WBYTES = 9 * 64 * 64 * 2;          // 73,728 B per weight tensor
    unsigned short* Wmap  = (unsigned short*)(wbase + 0 * WBYTES);
    unsigned short* Wu1   = (unsigned short*)(wbase + 1 * WBYTES);
    unsigned short* Wu2   = (unsigned short*)(wbase + 2 * WBYTES);
    unsigned short* Wug1  = (unsigned short*)(wbase + 3 * WBYTES);
    unsigned short* Wug2  = (unsigned short*)(wbase + 4 * WBYTES);
    unsigned short* Wb1a  = (unsigned short*)(wbase + 5 * WBYTES);
    unsigned short* Wb1b  = (unsigned short*)(wbase + 6 * WBYTES);
    unsigned short* Wbg1a = (unsigned short*)(wbase + 7 * WBYTES);
    unsigned short* Wbg1b = (unsigned short*)(wbase + 8 * WBYTES);
    unsigned short* Wb2   = (unsigned short*)(wbase + 9 * WBYTES);
    unsigned short* Wbg2  = (unsigned short*)(wbase + 10 * WBYTES);

    // --- prep: weights repack + Xpad build (one launch) ---
    WPrepBatch wb;
    wb.w[0]  = { w_map, Wmap,  33,  0, 33 };
    wb.w[1]  = { w_u1,  Wu1,   64,  0, 64 };
    wb.w[2]  = { w_u2,  Wu2,   64,  0, 64 };
    wb.w[3]  = { w_ug1, Wug1,  64,  0, 64 };
    wb.w[4]  = { w_ug2, Wug2,  64,  0, 64 };
    wb.w[5]  = { w_b1,  Wb1a, 128,  0, 64 };
    wb.w[6]  = { w_b1,  Wb1b, 128, 64, 64 };
    wb.w[7]  = { w_bg1, Wbg1a,128,  0, 64 };
    wb.w[8]  = { w_bg1, Wbg1b,128, 64, 64 };
    wb.w[9]  = { w_b2,  Wb2,   64,  0, 64 };
    wb.w[10] = { w_bg2, Wbg2,  64,  0, 64 };
    prep_k<<<dim3(1584 + 2560), dim3(256), 0, stream>>>(wb, x, t, Xpad);

    // --- map conv: h = conv(Xpad, w_map) + b_map ---
    ConvBatch cm{};
    cm.d[0] = { (const uint4*)Xpad, (const uint4*)Wmap, b_map, h, 0 };
    for (int i = 1; i < 6; ++i) cm.d[i] = cm.d[0];
    conv_mfma_k<<<dim3(NIMG, 1, 2), dim3(256), 0, stream>>>(cm);

    // --- stage 1: six convs from h ---
    ConvBatch c1{};
    c1.d[0] = { (const uint4*)h, (const uint4*)Wu1,   b_u1,  p1,    1 };
    c1.d[1] = { (const uint4*)h, (const uint4*)Wug1,  b_ug1, pg1,   1 };
    c1.d[2] = { (const uint4*)h, (const uint4*)Wb1a,  b_b1,  Abuf,  0 };
    c1.d[3] = { (const uint4*)h, (const uint4*)Wb1b,  nullptr, Bbuf, 0 };
    c1.d[4] = { (const uint4*)h, (const uint4*)Wbg1a, b_bg1, Agbuf, 0 };
    c1.d[5] = { (const uint4*)h, (const uint4*)Wbg1b, nullptr, Bgbuf, 0 };
    conv_mfma_k<<<dim3(NIMG, 6, 2), dim3(256), 0, stream>>>(c1);

    // --- stage 2: u_lin, ug_lin ---
    ConvBatch c2{};
    c2.d[0] = { (const uint4*)p1,  (const uint4*)Wu2,  b_u2,  u_lin,  0 };
    c2.d[1] = { (const uint4*)pg1, (const uint4*)Wug2, b_ug2, ug_lin, 0 };
    for (int i = 2; i < 6; ++i) c2.d[i] = c2.d[0];
    conv_mfma_k<<<dim3(NIMG, 2, 2), dim3(256), 0, stream>>>(c2);

    // --- pairwise messages -> bf16 partial slabs ---
    pair_mfma_k<<<dim3(400), dim3(512), 0, stream>>>(
        (const uint4*)Abuf, (const uint4*)Bbuf, (const uint4*)Agbuf, (const uint4*)Bgbuf,
        (const uint4*)Wb2, (const uint4*)Wbg2, b_b2, b_bg2, partials);

    // --- final combine ---
    final_k<<<dim3(NIMG), dim3(512), 0, stream>>>(u_lin, ug_lin, partials, out);
}

// Round 7
// 90.666 us; speedup vs baseline: 2.3881x; 2.3220x over previous
//
#include <hip/hip_runtime.h>
#include <math.h>

// N=2, K=20 -> 40 images; C=64 channels; 16x16 images (256 px).
#define NIMG 40
#define PXI  256
#define CH   64
#define SB_ELEM (NIMG * PXI * CH)   // 655360 elems per activation tensor
#define ZEROOFF 32768u              // byte offset of the 16B zero slot in LDS Z

typedef __bf16 bf16x8 __attribute__((ext_vector_type(8)));
typedef float  f32x4  __attribute__((ext_vector_type(4)));

static __device__ __forceinline__ unsigned short f2bf(float f) {
    unsigned u = __builtin_bit_cast(unsigned, f);
    u += 0x7fffu + ((u >> 16) & 1u);          // RNE
    return (unsigned short)(u >> 16);
}
static __device__ __forceinline__ unsigned pk2(float a, float b) {
    return (unsigned)f2bf(a) | ((unsigned)f2bf(b) << 16);
}
static __device__ __forceinline__ float bfu2f(unsigned hs) {  // bf16 bits in low 16
    unsigned u = (hs & 0xffffu) << 16;
    return __builtin_bit_cast(float, u);
}

// ===========================================================================
// Weight layout (coalesced, produced by prep_k):
//   uint4 index = ((kk*2+kh)*4 + oct)*64 + lane
//   element j of that uint4: oc = oct*16 + (lane&15), ci = (kh*4+(lane>>4))*8+j
// One B-fragment = one contiguous 1KB wave load.
// LDS Z swizzle: pixel pix, 16B ci-group g at slot pix*8 + (g ^ (pix&7)).
// ===========================================================================

// ---------------------------------------------------------------------------
// Stage-conv core (R6, proven): wave computes R rows x O oc-tiles.
// ---------------------------------------------------------------------------
template<int R, int O>
static __device__ __forceinline__ void conv_core(const char* __restrict__ zb,
                                                 const uint4* __restrict__ Wt,
                                                 int octg0, int r0, int lane,
                                                 const unsigned base[2][3],
                                                 const unsigned step[3],
                                                 f32x4 (&acc)[R][O])
{
#pragma unroll
    for (int kx = 0; kx < 3; ++kx)
#pragma unroll
        for (int kh = 0; kh < 2; ++kh) {
            uint4 w[3][O];
#pragma unroll
            for (int ky = 0; ky < 3; ++ky)
#pragma unroll
                for (int o = 0; o < O; ++o)
                    w[ky][o] = Wt[(((ky * 3 + kx) * 2 + kh) * 4 + octg0 + o) * 64 + lane];
#pragma unroll
            for (int dd = 0; dd < R + 2; ++dd) {
                const int ri = r0 + dd - 1;          // input row (wave-uniform)
                if (ri >= 0 && ri < 16) {
                    uint4 a = *(const uint4*)(zb + (base[kh][kx] + (unsigned)ri * step[kx]));
                    bf16x8 af = __builtin_bit_cast(bf16x8, a);
#pragma unroll
                    for (int ky = 0; ky < 3; ++ky) {
                        const int orow = dd - ky;
                        if (orow < 0 || orow >= R) continue;
#pragma unroll
                        for (int o = 0; o < O; ++o)
                            acc[orow][o] = __builtin_amdgcn_mfma_f32_16x16x32_bf16(
                                af, __builtin_bit_cast(bf16x8, w[ky][o]), acc[orow][o], 0, 0, 0);
                    }
                }
            }
        }
}

static __device__ __forceinline__ void make_base(unsigned base[2][3], unsigned step[3],
                                                 int l15, int l4)
{
#pragma unroll
    for (int kx = 0; kx < 3; ++kx) {
        const int xi = l15 + kx - 1;
        const bool valid = (unsigned)xi < 16u;
        step[kx] = valid ? 2048u : 0u;
#pragma unroll
        for (int kh = 0; kh < 2; ++kh) {
            const int g = kh * 4 + l4;
            base[kh][kx] = valid ? (unsigned)(xi * 128 + (((g ^ (xi & 7))) << 4))
                                 : ZEROOFF;
        }
    }
}

// ---------------------------------------------------------------------------
// Stage convs (R6, proven): X bf16 [img][256][64] -> out bf16 [img][256][64].
// 256 thr = 4 waves (rg = wv&1: 4 rows, op = wv>>1: 2 octs), grid (img, desc, half).
// ---------------------------------------------------------------------------
struct ConvDesc {
    const uint4* X;
    const uint4* W;
    const float* bias;      // nullptr -> no bias
    unsigned short* out;
    int relu;
};
struct ConvBatch { ConvDesc d[6]; };

__global__ __launch_bounds__(256)
void conv_mfma_k(ConvBatch cb)
{
    __shared__ uint4 Z[2049];
    const ConvDesc d = cb.d[blockIdx.y];
    const int img = blockIdx.x;
    const int tid = threadIdx.x;

    const uint4* Xi = d.X + img * 2048;
#pragma unroll
    for (int i = 0; i < 8; ++i) {
        int u = i * 256 + tid;
        int px = u >> 3, g = u & 7;
        Z[px * 8 + (g ^ (px & 7))] = Xi[u];
    }
    if (tid == 0) { uint4 z4 = {0u, 0u, 0u, 0u}; Z[2048] = z4; }
    __syncthreads();

    const int lane = tid & 63, wv = tid >> 6;
    const int l15 = lane & 15, l4 = lane >> 4;
    const int rg = wv & 1, op = wv >> 1;
    const int r0 = blockIdx.z * 8 + rg * 4;

    unsigned base[2][3], step[3];
    make_base(base, step, l15, l4);

    f32x4 acc[4][2];
    const f32x4 zz = {0.f, 0.f, 0.f, 0.f};
#pragma unroll
    for (int r = 0; r < 4; ++r)
#pragma unroll
        for (int o = 0; o < 2; ++o) acc[r][o] = zz;

    conv_core<4, 2>((const char*)Z, d.W, op * 2, r0, lane, base, step, acc);

#pragma unroll
    for (int o = 0; o < 2; ++o) {
        const int oc = (op * 2 + o) * 16 + l15;
        const float b = d.bias ? d.bias[oc] : 0.f;
#pragma unroll
        for (int r = 0; r < 4; ++r)
#pragma unroll
            for (int e = 0; e < 4; ++e) {
                float v = acc[r][o][e] + b;
                if (d.relu) v = fmaxf(v, 0.f);
                const int px = (r0 + r) * 16 + l4 * 4 + e;
                d.out[(img * PXI + px) * CH + oc] = f2bf(v);
            }
    }
}

// ---------------------------------------------------------------------------
// Pair kernel: R4 structure (proven no-spill) + coalesced weight loads.
// Block (imgb, s): dual-source Z0/Z1 in LDS; msg pass -> bf16 stash ->
// gate pass -> combine -> uint2 stores to partials[s][img][oc][px].
// Each weight fragment feeds 2 sources x 2 rows = 4 MFMAs.
// ---------------------------------------------------------------------------
static __device__ __forceinline__ void conv_tiles2_dual(
    const uint4* __restrict__ Z0, const uint4* __restrict__ Z1,
    const uint4* __restrict__ Wt, int y0, int lane, f32x4 acc[2][2][4])
{
    const int l15 = lane & 15;
    const int l4  = lane >> 4;
#pragma unroll
    for (int kh = 0; kh < 2; ++kh) {
        const int g = kh * 4 + l4;
#pragma unroll
        for (int kk = 0; kk < 9; ++kk) {
            const int ky = kk / 3 - 1;
            const int kx = kk % 3 - 1;
            bf16x8 bfrag[4];
#pragma unroll
            for (int oct = 0; oct < 4; ++oct)
                bfrag[oct] = __builtin_bit_cast(bf16x8,
                    Wt[((kk * 2 + kh) * 4 + oct) * 64 + lane]);   // contiguous 1KB load
#pragma unroll
            for (int r = 0; r < 2; ++r) {
                const int yy = y0 + r + ky;
                const int xx = l15 + kx;
                const bool inb = ((unsigned)yy < 16u) && ((unsigned)xx < 16u);
                const int pix = inb ? (yy * 16 + xx) : 0;
                const int slot = pix * 8 + (g ^ (pix & 7));
                uint4 a0 = Z0[slot];
                uint4 a1 = Z1[slot];
                if (!inb) {
                    a0.x = a0.y = a0.z = a0.w = 0u;
                    a1.x = a1.y = a1.z = a1.w = 0u;
                }
                bf16x8 f0 = __builtin_bit_cast(bf16x8, a0);
                bf16x8 f1 = __builtin_bit_cast(bf16x8, a1);
#pragma unroll
                for (int oct = 0; oct < 4; ++oct) {
                    acc[0][r][oct] = __builtin_amdgcn_mfma_f32_16x16x32_bf16(
                        f0, bfrag[oct], acc[0][r][oct], 0, 0, 0);
                    acc[1][r][oct] = __builtin_amdgcn_mfma_f32_16x16x32_bf16(
                        f1, bfrag[oct], acc[1][r][oct], 0, 0, 0);
                }
            }
        }
    }
}

static __device__ __forceinline__ uint4 relu_add4(uint4 a, uint4 b) {
    uint4 o;
    unsigned* ap = &a.x; unsigned* bp = &b.x; unsigned* op2 = &o.x;
#pragma unroll
    for (int w = 0; w < 4; ++w) {
        float a0 = __builtin_bit_cast(float, ap[w] << 16);
        float a1 = __builtin_bit_cast(float, ap[w] & 0xffff0000u);
        float b0 = __builtin_bit_cast(float, bp[w] << 16);
        float b1 = __builtin_bit_cast(float, bp[w] & 0xffff0000u);
        op2[w] = pk2(fmaxf(a0 + b0, 0.f), fmaxf(a1 + b1, 0.f));
    }
    return o;
}

__global__ __launch_bounds__(512)
void pair_mfma_k(const uint4* __restrict__ Abf, const uint4* __restrict__ Bbf,
                 const uint4* __restrict__ Agbf, const uint4* __restrict__ Bgbf,
                 const uint4* __restrict__ W2, const uint4* __restrict__ Wg2,
                 const float* __restrict__ b2, const float* __restrict__ bg2,
                 unsigned short* __restrict__ partials)
{
    __shared__ uint4 Z[2][2048];
    // XCD-chunked bijective swizzle (400 % 8 == 0)
    const int bi0 = blockIdx.x;
    const int bi  = (bi0 & 7) * 50 + (bi0 >> 3);
    const int imgb = bi / 10;
    const int s    = bi % 10;
    const int n    = imgb / 20;
    const int tid  = threadIdx.x;
    const int lane = tid & 63, wv = tid >> 6;
    const int l15 = lane & 15, l4 = lane >> 4;
    const int imga0 = n * 20 + s * 2;

    // ---- build msg inputs: Z0 = relu(A[b]+B[a0]), Z1 = relu(A[b]+B[a1]) ----
    {
        const uint4* Ap = Abf + imgb * 2048;
        const uint4* B0 = Bbf + imga0 * 2048;
        const uint4* B1 = B0 + 2048;
#pragma unroll
        for (int i = 0; i < 4; ++i) {
            int u = i * 512 + tid;
            uint4 a = Ap[u];
            int slot = (u >> 3) * 8 + ((u & 7) ^ ((u >> 3) & 7));
            Z[0][slot] = relu_add4(a, B0[u]);
            Z[1][slot] = relu_add4(a, B1[u]);
        }
    }
    __syncthreads();

    f32x4 zz = {0.f, 0.f, 0.f, 0.f};
    f32x4 acc[2][2][4];
#pragma unroll
    for (int ia = 0; ia < 2; ++ia)
#pragma unroll
        for (int r = 0; r < 2; ++r)
#pragma unroll
            for (int o = 0; o < 4; ++o) acc[ia][r][o] = zz;

    conv_tiles2_dual(Z[0], Z[1], W2, wv * 2, lane, acc);

    // ---- stash msg (+bias) as bf16 in registers ----
    float bmv[4];
#pragma unroll
    for (int oct = 0; oct < 4; ++oct) bmv[oct] = b2[oct * 16 + l15];
    unsigned mst[2][2][4][2];
#pragma unroll
    for (int ia = 0; ia < 2; ++ia)
#pragma unroll
        for (int r = 0; r < 2; ++r)
#pragma unroll
            for (int oct = 0; oct < 4; ++oct) {
                mst[ia][r][oct][0] = pk2(acc[ia][r][oct][0] + bmv[oct],
                                         acc[ia][r][oct][1] + bmv[oct]);
                mst[ia][r][oct][1] = pk2(acc[ia][r][oct][2] + bmv[oct],
                                         acc[ia][r][oct][3] + bmv[oct]);
            }

    __syncthreads();   // everyone done reading Z before overwrite

    // ---- build gate inputs ----
    {
        const uint4* Ap = Agbf + imgb * 2048;
        const uint4* B0 = Bgbf + imga0 * 2048;
        const uint4* B1 = B0 + 2048;
#pragma unroll
        for (int i = 0; i < 4; ++i) {
            int u = i * 512 + tid;
            uint4 a = Ap[u];
            int slot = (u >> 3) * 8 + ((u & 7) ^ ((u >> 3) & 7));
            Z[0][slot] = relu_add4(a, B0[u]);
            Z[1][slot] = relu_add4(a, B1[u]);
        }
    }
    __syncthreads();

#pragma unroll
    for (int ia = 0; ia < 2; ++ia)
#pragma unroll
        for (int r = 0; r < 2; ++r)
#pragma unroll
            for (int o = 0; o < 4; ++o) acc[ia][r][o] = zz;

    conv_tiles2_dual(Z[0], Z[1], Wg2, wv * 2, lane, acc);

    // ---- combine: out = sum_ia msg * sigmoid(gate), store 8B per lane ----
    float bgv[4];
#pragma unroll
    for (int oct = 0; oct < 4; ++oct) bgv[oct] = bg2[oct * 16 + l15];

    const int base = (s * NIMG + imgb) * (PXI * CH);
#pragma unroll
    for (int r = 0; r < 2; ++r)
#pragma unroll
        for (int oct = 0; oct < 4; ++oct) {
            float o[4] = {0.f, 0.f, 0.f, 0.f};
#pragma unroll
            for (int ia = 0; ia < 2; ++ia)
#pragma unroll
                for (int e = 0; e < 4; ++e) {
                    float gt = acc[ia][r][oct][e] + bgv[oct];
                    float msg = bfu2f(mst[ia][r][oct][e >> 1] >> ((e & 1) * 16));
                    o[e] += msg * (1.f / (1.f + __expf(-gt)));
                }
            uint2 pkd;
            pkd.x = pk2(o[0], o[1]);
            pkd.y = pk2(o[2], o[3]);
            const int px0 = (wv * 2 + r) * 16 + l4 * 4;
            const int oc  = oct * 16 + l15;
            *(uint2*)&partials[base + oc * PXI + px0] = pkd;
        }
}

// ---------------------------------------------------------------------------
// Merged prep (R6): weight repack into coalesced layout + X padding.
// ---------------------------------------------------------------------------
struct WPrep { const float* src; unsigned short* dst; int cin_src; int cioff; int nvalid; };
struct WPrepBatch { WPrep w[11]; };

__global__ __launch_bounds__(256)
void prep_k(WPrepBatch wb, const float* __restrict__ x, const float* __restrict__ t,
            unsigned short* __restrict__ Xpad)
{
    const int bx = blockIdx.x;
    if (bx < 1584) {
        const WPrep p = wb.w[bx / 144];
        const int e = (bx % 144) * 256 + threadIdx.x;   // 0..36863
        const int j = e & 7;
        const int u4 = e >> 3;
        const int lane = u4 & 63;
        const int oct = (u4 >> 6) & 3;
        const int kh  = (u4 >> 8) & 1;
        const int kk  = u4 >> 9;
        const int oc  = oct * 16 + (lane & 15);
        const int ci  = (kh * 4 + (lane >> 4)) * 8 + j;
        float v = 0.f;
        if (ci < p.nvalid)
            v = p.src[(oc * p.cin_src + p.cioff + ci) * 9 + kk];
        p.dst[e] = f2bf(v);
    } else {
        const int idx = (bx - 1584) * 256 + threadIdx.x;  // 0..655359
        const int img = idx >> 14;
        const int px  = (idx >> 6) & 255;
        const int ch  = idx & 63;
        float v;
        if (ch == 0)       v = t[0];
        else if (ch <= 32) v = x[((img * 32) + (ch - 1)) * PXI + px];
        else               v = 0.f;
        Xpad[idx] = f2bf(v);
    }
}

// ---------------------------------------------------------------------------
// Final: out[img][oc][px] = u*sigmoid(ug) + (sum_s partials[s])/19.
// ---------------------------------------------------------------------------
__global__ __launch_bounds__(512)
void final_k(const unsigned short* __restrict__ u_lin,
             const unsigned short* __restrict__ ug_lin,
             const unsigned short* __restrict__ P,
             float* __restrict__ out)
{
    __shared__ float buf[PXI * 65];
    const int img = blockIdx.x;
    const int tid = threadIdx.x;

#pragma unroll
    for (int i = 0; i < 32; ++i) {
        const int idx = i * 512 + tid;          // [px][oc], oc innermost
        const int px = idx >> 6, oc = idx & 63;
        const float u = bfu2f(u_lin[img * (PXI * CH) + idx]);
        const float g = bfu2f(ug_lin[img * (PXI * CH) + idx]);
        buf[px * 65 + oc] = u * (1.f / (1.f + __expf(-g)));
    }
    __syncthreads();
#pragma unroll
    for (int i = 0; i < 32; ++i) {
        const int j = i * 512 + tid;            // [oc][px], px innermost
        const int oc = j >> 8, px = j & 255;
        float ssum = 0.f;
#pragma unroll
        for (int sl = 0; sl < 10; ++sl)
            ssum += bfu2f(P[(sl * NIMG + img) * (PXI * CH) + j]);
        out[img * (PXI * CH) + j] = buf[px * 65 + oc] + ssum * (1.f / 19.f);
    }
}

// ---------------------------------------------------------------------------
extern "C" void kernel_launch(void* const* d_in, const int* in_sizes, int n_in,
                              void* d_out, int out_size, void* d_ws, size_t ws_size,
                              hipStream_t stream)
{
    const float* t     = (const float*)d_in[0];
    const float* x     = (const float*)d_in[1];
    const float* w_map = (const float*)d_in[2];
    const float* b_map = (const float*)d_in[3];
    const float* w_u1  = (const float*)d_in[4];
    const float* b_u1  = (const float*)d_in[5];
    const float* w_u2  = (const float*)d_in[6];
    const float* b_u2  = (const float*)d_in[7];
    const float* w_ug1 = (const float*)d_in[8];
    const float* b_ug1 = (const float*)d_in[9];
    const float* w_ug2 = (const float*)d_in[10];
    const float* b_ug2 = (const float*)d_in[11];
    const float* w_b1  = (const float*)d_in[12];
    const float* b_b1  = (const float*)d_in[13];
    const float* w_b2  = (const float*)d_in[14];
    const float* b_b2  = (const float*)d_in[15];
    const float* w_bg1 = (const float*)d_in[16];
    const float* b_bg1 = (const float*)d_in[17];
    const float* w_bg2 = (const float*)d_in[18];
    const float* b_bg2 = (const float*)d_in[19];

    float* out = (float*)d_out;
    char* ws = (char*)d_ws;

    const size_t ABYTES = (size_t)SB_ELEM * 2;      // 1,310,720 B per bf16 tensor

    // Partials (10 bf16 slabs) overlay slabs 0..9; Xpad/h/p1/pg1 live in the
    // first 4 and are dead before pair_mfma_k runs (stream order).
    unsigned short* partials = (unsigned short*)(ws);
    unsigned short* Xpad   = (unsigned short*)(ws + 0 * ABYTES);
    unsigned short* h      = (unsigned short*)(ws + 1 * ABYTES);
    unsigned short* p1     = (unsigned short*)(ws + 2 * ABYTES);
    unsigned short* pg1    = (unsigned short*)(ws + 3 * ABYTES);
    unsigned short* u_lin  = (unsigned short*)(ws + 10 * ABYTES);
    unsigned short* ug_lin = (unsigned short*)(ws + 11 * ABYTES);
    unsigned short* Abuf   = (unsigned short*)(ws + 12 * ABYTES);
    unsigned short* Bbuf   = (unsigned short*)(ws + 13 * ABYTES);
    unsigned short* Agbuf  = (unsigned short*)(ws + 14 * ABYTES);
    unsigned short* Bgbuf  = (unsigned short*)(ws + 15 * ABYTES);
    char* wbase = ws + 16 * ABYTES;                 // ~21 MB
    const size_t WBYTES = 9 * 64 * 64 * 2;          // 73,728 B per weight tensor
    unsigned short* Wmap  = (unsigned short*)(wbase + 0 * WBYTES);
    unsigned short* Wu1   = (unsigned short*)(wbase + 1 * WBYTES);
    unsigned short* Wu2   = (unsigned short*)(wbase + 2 * WBYTES);
    unsigned short* Wug1  = (unsigned short*)(wbase + 3 * WBYTES);
    unsigned short* Wug2  = (unsigned short*)(wbase + 4 * WBYTES);
    unsigned short* Wb1a  = (unsigned short*)(wbase + 5 * WBYTES);
    unsigned short* Wb1b  = (unsigned short*)(wbase + 6 * WBYTES);
    unsigned short* Wbg1a = (unsigned short*)(wbase + 7 * WBYTES);
    unsigned short* Wbg1b = (unsigned short*)(wbase + 8 * WBYTES);
    unsigned short* Wb2   = (unsigned short*)(wbase + 9 * WBYTES);
    unsigned short* Wbg2  = (unsigned short*)(wbase + 10 * WBYTES);

    // --- prep: weights repack + Xpad build (one launch) ---
    WPrepBatch wb;
    wb.w[0]  = { w_map, Wmap,  33,  0, 33 };
    wb.w[1]  = { w_u1,  Wu1,   64,  0, 64 };
    wb.w[2]  = { w_u2,  Wu2,   64,  0, 64 };
    wb.w[3]  = { w_ug1, Wug1,  64,  0, 64 };
    wb.w[4]  = { w_ug2, Wug2,  64,  0, 64 };
    wb.w[5]  = { w_b1,  Wb1a, 128,  0, 64 };
    wb.w[6]  = { w_b1,  Wb1b, 128, 64, 64 };
    wb.w[7]  = { w_bg1, Wbg1a,128,  0, 64 };
    wb.w[8]  = { w_bg1, Wbg1b,128, 64, 64 };
    wb.w[9]  = { w_b2,  Wb2,   64,  0, 64 };
    wb.w[10] = { w_bg2, Wbg2,  64,  0, 64 };
    prep_k<<<dim3(1584 + 2560), dim3(256), 0, stream>>>(wb, x, t, Xpad);

    // --- map conv: h = conv(Xpad, w_map) + b_map ---
    ConvBatch cm{};
    cm.d[0] = { (const uint4*)Xpad, (const uint4*)Wmap, b_map, h, 0 };
    for (int i = 1; i < 6; ++i) cm.d[i] = cm.d[0];
    conv_mfma_k<<<dim3(NIMG, 1, 2), dim3(256), 0, stream>>>(cm);

    // --- stage 1: six convs from h ---
    ConvBatch c1{};
    c1.d[0] = { (const uint4*)h, (const uint4*)Wu1,   b_u1,  p1,    1 };
    c1.d[1] = { (const uint4*)h, (const uint4*)Wug1,  b_ug1, pg1,   1 };
    c1.d[2] = { (const uint4*)h, (const uint4*)Wb1a,  b_b1,  Abuf,  0 };
    c1.d[3] = { (const uint4*)h, (const uint4*)Wb1b,  nullptr, Bbuf, 0 };
    c1.d[4] = { (const uint4*)h, (const uint4*)Wbg1a, b_bg1, Agbuf, 0 };
    c1.d[5] = { (const uint4*)h, (const uint4*)Wbg1b, nullptr, Bgbuf, 0 };
    conv_mfma_k<<<dim3(NIMG, 6, 2), dim3(256), 0, stream>>>(c1);

    // --- stage 2: u_lin, ug_lin ---
    ConvBatch c2{};
    c2.d[0] = { (const uint4*)p1,  (const uint4*)Wu2,  b_u2,  u_lin,  0 };
    c2.d[1] = { (const uint4*)pg1, (const uint4*)Wug2, b_ug2, ug_lin, 0 };
    for (int i = 2; i < 6; ++i) c2.d[i] = c2.d[0];
    conv_mfma_k<<<dim3(NIMG, 2, 2), dim3(256), 0, stream>>>(c2);

    // --- pairwise messages -> bf16 partial slabs ---
    pair_mfma_k<<<dim3(400), dim3(512), 0, stream>>>(
        (const uint4*)Abuf, (const uint4*)Bbuf, (const uint4*)Agbuf, (const uint4*)Bgbuf,
        (const uint4*)Wb2, (const uint4*)Wbg2, b_b2, b_bg2, partials);

    // --- final combine ---
    final_k<<<dim3(NIMG), dim3(512), 0, stream>>>(u_lin, ug_lin, partials, out);
}

// Round 10
// 85.646 us; speedup vs baseline: 2.5280x; 1.0586x over previous
//
#include <hip/hip_runtime.h>
#include <math.h>

// N=2, K=20 -> 40 images; C=64 channels; 16x16 images (256 px).
#define NIMG 40
#define PXI  256
#define CH   64
#define SB_ELEM (NIMG * PXI * CH)   // 655360 elems per activation tensor
#define ZEROOFF 32768u              // byte offset of zero slot (stage-conv paths)

typedef __bf16 bf16x8 __attribute__((ext_vector_type(8)));
typedef float  f32x4  __attribute__((ext_vector_type(4)));

static __device__ __forceinline__ unsigned short f2bf(float f) {
    unsigned u = __builtin_bit_cast(unsigned, f);
    u += 0x7fffu + ((u >> 16) & 1u);          // RNE
    return (unsigned short)(u >> 16);
}
static __device__ __forceinline__ unsigned cvtpk(float lo, float hi) {
    unsigned r;
    asm("v_cvt_pk_bf16_f32 %0, %1, %2" : "=v"(r) : "v"(lo), "v"(hi));
    return r;
}
static __device__ __forceinline__ float bfu2f(unsigned hs) {  // bf16 bits in low 16
    unsigned u = (hs & 0xffffu) << 16;
    return __builtin_bit_cast(float, u);
}
static __device__ __forceinline__ float sigm(float x) {
    return 1.f / (1.f + __expf(-x));
}

// ===========================================================================
// Weight layout (coalesced): uint4 index = ((kk*2+kh)*4 + oct)*64 + lane;
// element j: oc = oct*16 + (lane&15), ci = (kh*4+(lane>>4))*8 + j.
// LDS Z swizzle: pixel pix, 16B ci-group g at byte pix*128 + ((g^(pix&7))<<4).
// pix&7 == xx&7 -> per-lane column base + yy*2048.
//
// WORKSPACE LIVENESS INVARIANT (G16): partials slabs 0..9 overlay
// Xpad/h/p1/pg1; ALL consumers of those (map, stage-1, stage-2 convs) must
// complete in launches BEFORE pair_mfma_k. Do NOT fuse stage-2 into the pair
// kernel (R8/R9 race).
// ===========================================================================

// ---------------------------------------------------------------------------
// Stage-conv core (R6/R7 proven): wave computes R rows x O oc-tiles.
// ---------------------------------------------------------------------------
template<int R, int O>
static __device__ __forceinline__ void conv_core(const char* __restrict__ zb,
                                                 const uint4* __restrict__ Wt,
                                                 int octg0, int r0, int lane,
                                                 const unsigned base[2][3],
                                                 const unsigned step[3],
                                                 f32x4 (&acc)[R][O])
{
#pragma unroll
    for (int kx = 0; kx < 3; ++kx)
#pragma unroll
        for (int kh = 0; kh < 2; ++kh) {
            uint4 w[3][O];
#pragma unroll
            for (int ky = 0; ky < 3; ++ky)
#pragma unroll
                for (int o = 0; o < O; ++o)
                    w[ky][o] = Wt[(((ky * 3 + kx) * 2 + kh) * 4 + octg0 + o) * 64 + lane];
#pragma unroll
            for (int dd = 0; dd < R + 2; ++dd) {
                const int ri = r0 + dd - 1;          // input row (wave-uniform)
                if (ri >= 0 && ri < 16) {
                    uint4 a = *(const uint4*)(zb + (base[kh][kx] + (unsigned)ri * step[kx]));
                    bf16x8 af = __builtin_bit_cast(bf16x8, a);
#pragma unroll
                    for (int ky = 0; ky < 3; ++ky) {
                        const int orow = dd - ky;
                        if (orow < 0 || orow >= R) continue;
#pragma unroll
                        for (int o = 0; o < O; ++o)
                            acc[orow][o] = __builtin_amdgcn_mfma_f32_16x16x32_bf16(
                                af, __builtin_bit_cast(bf16x8, w[ky][o]), acc[orow][o], 0, 0, 0);
                    }
                }
            }
        }
}

static __device__ __forceinline__ void make_base(unsigned base[2][3], unsigned step[3],
                                                 int l15, int l4)
{
#pragma unroll
    for (int kx = 0; kx < 3; ++kx) {
        const int xi = l15 + kx - 1;
        const bool valid = (unsigned)xi < 16u;
        step[kx] = valid ? 2048u : 0u;
#pragma unroll
        for (int kh = 0; kh < 2; ++kh) {
            const int g = kh * 4 + l4;
            base[kh][kx] = valid ? (unsigned)(xi * 128 + (((g ^ (xi & 7))) << 4))
                                 : ZEROOFF;
        }
    }
}

// pair variant: invalid-x lanes get base=0 (in-bounds) + xmask=0 (value AND).
static __device__ __forceinline__ void make_base_pair(unsigned base[2][3], unsigned xmask[3],
                                                      int l15, int l4)
{
#pragma unroll
    for (int kx = 0; kx < 3; ++kx) {
        const int xi = l15 + kx - 1;
        const bool valid = (unsigned)xi < 16u;
        xmask[kx] = valid ? 0xFFFFFFFFu : 0u;
#pragma unroll
        for (int kh = 0; kh < 2; ++kh) {
            const int g = kh * 4 + l4;
            base[kh][kx] = valid ? (unsigned)(xi * 128 + (((g ^ (xi & 7))) << 4))
                                 : 0u;
        }
    }
}

// ---------------------------------------------------------------------------
// Stage convs (map + stage1 + stage2): 256 thr = 4 waves, grid (img, desc, half).
// ---------------------------------------------------------------------------
struct ConvDesc {
    const uint4* X;
    const uint4* W;
    const float* bias;      // nullptr -> no bias
    unsigned short* out;
    int relu;
};
struct ConvBatch { ConvDesc d[6]; };

__global__ __launch_bounds__(256)
void conv_mfma_k(ConvBatch cb)
{
    __shared__ uint4 Z[2049];
    const ConvDesc d = cb.d[blockIdx.y];
    const int img = blockIdx.x;
    const int tid = threadIdx.x;

    const uint4* Xi = d.X + img * 2048;
#pragma unroll
    for (int i = 0; i < 8; ++i) {
        int u = i * 256 + tid;
        int px = u >> 3, g = u & 7;
        Z[px * 8 + (g ^ (px & 7))] = Xi[u];
    }
    if (tid == 0) { uint4 z4 = {0u, 0u, 0u, 0u}; Z[2048] = z4; }
    __syncthreads();

    const int lane = tid & 63, wv = tid >> 6;
    const int l15 = lane & 15, l4 = lane >> 4;
    const int rg = wv & 1, op = wv >> 1;
    const int r0 = blockIdx.z * 8 + rg * 4;

    unsigned base[2][3], step[3];
    make_base(base, step, l15, l4);

    f32x4 acc[4][2];
    const f32x4 zz = {0.f, 0.f, 0.f, 0.f};
#pragma unroll
    for (int r = 0; r < 4; ++r)
#pragma unroll
        for (int o = 0; o < 2; ++o) acc[r][o] = zz;

    conv_core<4, 2>((const char*)Z, d.W, op * 2, r0, lane, base, step, acc);

#pragma unroll
    for (int o = 0; o < 2; ++o) {
        const int oc = (op * 2 + o) * 16 + l15;
        const float b = d.bias ? d.bias[oc] : 0.f;
#pragma unroll
        for (int r = 0; r < 4; ++r)
#pragma unroll
            for (int e = 0; e < 4; ++e) {
                float v = acc[r][o][e] + b;
                if (d.relu) v = fmaxf(v, 0.f);
                const int px = (r0 + r) * 16 + l4 * 4 + e;
                d.out[(img * PXI + px) * CH + oc] = f2bf(v);
            }
    }
}

// ---------------------------------------------------------------------------
// Pair dual-source conv: per (kh,kk): 4 coalesced W-frags; per r one addr;
// y-border = wave-uniform skip; x-border = AND loaded value with xmask.
// Z0 at slots 0..2047, Z1 at 2048..4095 (imm +32768 on the same address).
// ---------------------------------------------------------------------------
static __device__ __forceinline__ void conv_dual(const char* __restrict__ zb,
                                                 const uint4* __restrict__ Wt,
                                                 int y0, int lane,
                                                 const unsigned base[2][3],
                                                 const unsigned xmask[3],
                                                 f32x4 acc[2][2][4])
{
#pragma unroll
    for (int kh = 0; kh < 2; ++kh)
#pragma unroll
        for (int kk = 0; kk < 9; ++kk) {
            const int kym = kk / 3, kx = kk % 3;
            bf16x8 bf[4];
#pragma unroll
            for (int oct = 0; oct < 4; ++oct)
                bf[oct] = __builtin_bit_cast(bf16x8, Wt[((kk * 2 + kh) * 4 + oct) * 64 + lane]);
#pragma unroll
            for (int r = 0; r < 2; ++r) {
                const int yy = y0 + r + kym - 1;     // wave-uniform
                if ((unsigned)yy < 16u) {
                    const unsigned addr = base[kh][kx] + ((unsigned)yy << 11);
                    uint4 a0 = *(const uint4*)(zb + addr);
                    uint4 a1 = *(const uint4*)(zb + addr + 32768u);
                    const unsigned m = xmask[kx];
                    a0.x &= m; a0.y &= m; a0.z &= m; a0.w &= m;
                    a1.x &= m; a1.y &= m; a1.z &= m; a1.w &= m;
                    bf16x8 f0 = __builtin_bit_cast(bf16x8, a0);
                    bf16x8 f1 = __builtin_bit_cast(bf16x8, a1);
#pragma unroll
                    for (int oct = 0; oct < 4; ++oct) {
                        acc[0][r][oct] = __builtin_amdgcn_mfma_f32_16x16x32_bf16(
                            f0, bf[oct], acc[0][r][oct], 0, 0, 0);
                        acc[1][r][oct] = __builtin_amdgcn_mfma_f32_16x16x32_bf16(
                            f1, bf[oct], acc[1][r][oct], 0, 0, 0);
                    }
                }
            }
        }
}

static __device__ __forceinline__ uint4 relu_add4(uint4 a, uint4 b) {
    uint4 o;
    unsigned* ap = &a.x; unsigned* bp = &b.x; unsigned* op2 = &o.x;
#pragma unroll
    for (int w = 0; w < 4; ++w) {
        float a0 = __builtin_bit_cast(float, ap[w] << 16);
        float a1 = __builtin_bit_cast(float, ap[w] & 0xffff0000u);
        float b0 = __builtin_bit_cast(float, bp[w] << 16);
        float b1 = __builtin_bit_cast(float, bp[w] & 0xffff0000u);
        op2[w] = cvtpk(fmaxf(a0 + b0, 0.f), fmaxf(a1 + b1, 0.f));
    }
    return o;
}

// ---------------------------------------------------------------------------
// Pair kernel (grid 400, 512 thr): (imgb, s) dual-source; odd s runs the gate
// pass first (anti-convoy). LDS: Z[4096] = 65536 B (Z0 0..2047, Z1 2048..4095).
// ---------------------------------------------------------------------------
__global__ __launch_bounds__(512)
void pair_mfma_k(const uint4* __restrict__ Abf, const uint4* __restrict__ Bbf,
                 const uint4* __restrict__ Agbf, const uint4* __restrict__ Bgbf,
                 const uint4* __restrict__ W2, const uint4* __restrict__ Wg2,
                 const float* __restrict__ b2, const float* __restrict__ bg2,
                 unsigned short* __restrict__ partials)
{
    __shared__ uint4 Z[4096];
    const char* zb = (const char*)Z;
    const int bx0 = blockIdx.x;
    const int tid = threadIdx.x;
    const int lane = tid & 63, wv = tid >> 6;
    const int l15 = lane & 15, l4 = lane >> 4;

    // XCD-chunked bijective swizzle (400 % 8 == 0)
    const int bi  = (bx0 & 7) * 50 + (bx0 >> 3);
    const int imgb = bi / 10;
    const int s    = bi % 10;
    const int n    = imgb / 20;
    const int gf   = s & 1;                  // gate-first stagger
    const int imga0 = n * 20 + s * 2;

    const uint4* A1; const uint4* B1; const uint4* Wp1;
    const uint4* A2; const uint4* B2; const uint4* Wp2;
    if (!gf) { A1 = Abf  + imgb * 2048; B1 = Bbf  + imga0 * 2048; Wp1 = W2;
               A2 = Agbf + imgb * 2048; B2 = Bgbf + imga0 * 2048; Wp2 = Wg2; }
    else     { A1 = Agbf + imgb * 2048; B1 = Bgbf + imga0 * 2048; Wp1 = Wg2;
               A2 = Abf  + imgb * 2048; B2 = Bbf  + imga0 * 2048; Wp2 = W2; }

    // ---- build pass-1 Z (both sources) ----
#pragma unroll
    for (int i = 0; i < 4; ++i) {
        int u = i * 512 + tid;
        int slot = (u >> 3) * 8 + ((u & 7) ^ ((u >> 3) & 7));
        uint4 a = A1[u];
        Z[slot]        = relu_add4(a, B1[u]);
        Z[2048 + slot] = relu_add4(a, B1[u + 2048]);
    }
    __syncthreads();

    unsigned base[2][3], xmask[3];
    make_base_pair(base, xmask, l15, l4);

    const f32x4 zz = {0.f, 0.f, 0.f, 0.f};
    f32x4 acc[2][2][4];
#pragma unroll
    for (int ia = 0; ia < 2; ++ia)
#pragma unroll
        for (int r = 0; r < 2; ++r)
#pragma unroll
            for (int o = 0; o < 4; ++o) acc[ia][r][o] = zz;

    conv_dual(zb, Wp1, wv * 2, lane, base, xmask, acc);

    float bmv[4], bgv[4];
#pragma unroll
    for (int oct = 0; oct < 4; ++oct) {
        bmv[oct] = b2[oct * 16 + l15];
        bgv[oct] = bg2[oct * 16 + l15];
    }

    // ---- stash pass-1 result as bf16 ----
    unsigned st[2][2][4][2];
    if (!gf) {
#pragma unroll
        for (int ia = 0; ia < 2; ++ia)
#pragma unroll
            for (int r = 0; r < 2; ++r)
#pragma unroll
                for (int oct = 0; oct < 4; ++oct) {
                    st[ia][r][oct][0] = cvtpk(acc[ia][r][oct][0] + bmv[oct],
                                              acc[ia][r][oct][1] + bmv[oct]);
                    st[ia][r][oct][1] = cvtpk(acc[ia][r][oct][2] + bmv[oct],
                                              acc[ia][r][oct][3] + bmv[oct]);
                }
    } else {
#pragma unroll
        for (int ia = 0; ia < 2; ++ia)
#pragma unroll
            for (int r = 0; r < 2; ++r)
#pragma unroll
                for (int oct = 0; oct < 4; ++oct) {
                    st[ia][r][oct][0] = cvtpk(sigm(acc[ia][r][oct][0] + bgv[oct]),
                                              sigm(acc[ia][r][oct][1] + bgv[oct]));
                    st[ia][r][oct][1] = cvtpk(sigm(acc[ia][r][oct][2] + bgv[oct]),
                                              sigm(acc[ia][r][oct][3] + bgv[oct]));
                }
    }
    __syncthreads();   // all reads of Z done

    // ---- build pass-2 Z ----
#pragma unroll
    for (int i = 0; i < 4; ++i) {
        int u = i * 512 + tid;
        int slot = (u >> 3) * 8 + ((u & 7) ^ ((u >> 3) & 7));
        uint4 a = A2[u];
        Z[slot]        = relu_add4(a, B2[u]);
        Z[2048 + slot] = relu_add4(a, B2[u + 2048]);
    }
    __syncthreads();

#pragma unroll
    for (int ia = 0; ia < 2; ++ia)
#pragma unroll
        for (int r = 0; r < 2; ++r)
#pragma unroll
            for (int o = 0; o < 4; ++o) acc[ia][r][o] = zz;

    conv_dual(zb, Wp2, wv * 2, lane, base, xmask, acc);

    // ---- combine + store: partials[s][img][oc][px] ----
    const int pbase = (s * NIMG + imgb) * (PXI * CH);
#pragma unroll
    for (int r = 0; r < 2; ++r)
#pragma unroll
        for (int oct = 0; oct < 4; ++oct) {
            float o[4] = {0.f, 0.f, 0.f, 0.f};
            if (!gf) {
#pragma unroll
                for (int ia = 0; ia < 2; ++ia)
#pragma unroll
                    for (int e = 0; e < 4; ++e) {
                        float gt = acc[ia][r][oct][e] + bgv[oct];
                        float m  = bfu2f(st[ia][r][oct][e >> 1] >> ((e & 1) * 16));
                        o[e] += m * sigm(gt);
                    }
            } else {
#pragma unroll
                for (int ia = 0; ia < 2; ++ia)
#pragma unroll
                    for (int e = 0; e < 4; ++e) {
                        float m  = acc[ia][r][oct][e] + bmv[oct];
                        float sg = bfu2f(st[ia][r][oct][e >> 1] >> ((e & 1) * 16));
                        o[e] += m * sg;
                    }
            }
            uint2 pkd;
            pkd.x = cvtpk(o[0], o[1]);
            pkd.y = cvtpk(o[2], o[3]);
            const int px0 = (wv * 2 + r) * 16 + l4 * 4;
            const int oc  = oct * 16 + l15;
            *(uint2*)&partials[pbase + oc * PXI + px0] = pkd;
        }
}

// ---------------------------------------------------------------------------
// Merged prep: weight repack (coalesced layout) + X padding.
// ---------------------------------------------------------------------------
struct WPrep { const float* src; unsigned short* dst; int cin_src; int cioff; int nvalid; };
struct WPrepBatch { WPrep w[11]; };

__global__ __launch_bounds__(256)
void prep_k(WPrepBatch wb, const float* __restrict__ x, const float* __restrict__ t,
            unsigned short* __restrict__ Xpad)
{
    const int bx = blockIdx.x;
    if (bx < 1584) {
        const WPrep p = wb.w[bx / 144];
        const int e = (bx % 144) * 256 + threadIdx.x;   // 0..36863
        const int j = e & 7;
        const int u4 = e >> 3;
        const int lane = u4 & 63;
        const int oct = (u4 >> 6) & 3;
        const int kh  = (u4 >> 8) & 1;
        const int kk  = u4 >> 9;
        const int oc  = oct * 16 + (lane & 15);
        const int ci  = (kh * 4 + (lane >> 4)) * 8 + j;
        float v = 0.f;
        if (ci < p.nvalid)
            v = p.src[(oc * p.cin_src + p.cioff + ci) * 9 + kk];
        p.dst[e] = f2bf(v);
    } else {
        const int idx = (bx - 1584) * 256 + threadIdx.x;  // 0..655359
        const int img = idx >> 14;
        const int px  = (idx >> 6) & 255;
        const int ch  = idx & 63;
        float v;
        if (ch == 0)       v = t[0];
        else if (ch <= 32) v = x[((img * 32) + (ch - 1)) * PXI + px];
        else               v = 0.f;
        Xpad[idx] = f2bf(v);
    }
}

// ---------------------------------------------------------------------------
// Final: out[img][oc][px] = u*sigmoid(ug) + (sum_s partials[s])/19.
// ---------------------------------------------------------------------------
__global__ __launch_bounds__(512)
void final_k(const unsigned short* __restrict__ u_lin,
             const unsigned short* __restrict__ ug_lin,
             const unsigned short* __restrict__ P,
             float* __restrict__ out)
{
    __shared__ float buf[PXI * 65];
    const int img = blockIdx.x;
    const int tid = threadIdx.x;

#pragma unroll
    for (int i = 0; i < 32; ++i) {
        const int idx = i * 512 + tid;          // [px][oc], oc innermost
        const int px = idx >> 6, oc = idx & 63;
        const float u = bfu2f(u_lin[img * (PXI * CH) + idx]);
        const float g = bfu2f(ug_lin[img * (PXI * CH) + idx]);
        buf[px * 65 + oc] = u * sigm(g);
    }
    __syncthreads();
#pragma unroll
    for (int i = 0; i < 32; ++i) {
        const int j = i * 512 + tid;            // [oc][px], px innermost
        const int oc = j >> 8, px = j & 255;
        float ssum = 0.f;
#pragma unroll
        for (int sl = 0; sl < 10; ++sl)
            ssum += bfu2f(P[(sl * NIMG + img) * (PXI * CH) + j]);
        out[img * (PXI * CH) + j] = buf[px * 65 + oc] + ssum * (1.f / 19.f);
    }
}

// ---------------------------------------------------------------------------
extern "C" void kernel_launch(void* const* d_in, const int* in_sizes, int n_in,
                              void* d_out, int out_size, void* d_ws, size_t ws_size,
                              hipStream_t stream)
{
    const float* t     = (const float*)d_in[0];
    const float* x     = (const float*)d_in[1];
    const float* w_map = (const float*)d_in[2];
    const float* b_map = (const float*)d_in[3];
    const float* w_u1  = (const float*)d_in[4];
    const float* b_u1  = (const float*)d_in[5];
    const float* w_u2  = (const float*)d_in[6];
    const float* b_u2  = (const float*)d_in[7];
    const float* w_ug1 = (const float*)d_in[8];
    const float* b_ug1 = (const float*)d_in[9];
    const float* w_ug2 = (const float*)d_in[10];
    const float* b_ug2 = (const float*)d_in[11];
    const float* w_b1  = (const float*)d_in[12];
    const float* b_b1  = (const float*)d_in[13];
    const float* w_b2  = (const float*)d_in[14];
    const float* b_b2  = (const float*)d_in[15];
    const float* w_bg1 = (const float*)d_in[16];
    const float* b_bg1 = (const float*)d_in[17];
    const float* w_bg2 = (const float*)d_in[18];
    const float* b_bg2 = (const float*)d_in[19];

    float* out = (float*)d_out;
    char* ws = (char*)d_ws;

    const size_t ABYTES = (size_t)SB_ELEM * 2;      // 1,310,720 B per bf16 tensor

    // Partials (10 bf16 slabs) overlay slabs 0..9; Xpad/h/p1/pg1 live in the
    // first 4 and are dead before pair_mfma_k runs (ALL their consumers --
    // map, stage-1, stage-2 -- are in earlier launches; see invariant above).
    unsigned short* partials = (unsigned short*)(ws);
    unsigned short* Xpad   = (unsigned short*)(ws + 0 * ABYTES);
    unsigned short* h      = (unsigned short*)(ws + 1 * ABYTES);
    unsigned short* p1     = (unsigned short*)(ws + 2 * ABYTES);
    unsigned short* pg1    = (unsigned short*)(ws + 3 * ABYTES);
    unsigned short* u_lin  = (unsigned short*)(ws + 10 * ABYTES);
    unsigned short* ug_lin = (unsigned short*)(ws + 11 * ABYTES);
    unsigned short* Abuf   = (unsigned short*)(ws + 12 * ABYTES);
    unsigned short* Bbuf   = (unsigned short*)(ws + 13 * ABYTES);
    unsigned short* Agbuf  = (unsigned short*)(ws + 14 * ABYTES);
    unsigned short* Bgbuf  = (unsigned short*)(ws + 15 * ABYTES);
    char* wbase = ws + 16 * ABYTES;                 // ~21 MB
    const size_t WBYTES = 9 * 64 * 64 * 2;          // 73,728 B per weight tensor
    unsigned short* Wmap  = (unsigned short*)(wbase + 0 * WBYTES);
    unsigned short* Wu1   = (unsigned short*)(wbase + 1 * WBYTES);
    unsigned short* Wu2   = (unsigned short*)(wbase + 2 * WBYTES);
    unsigned short* Wug1  = (unsigned short*)(wbase + 3 * WBYTES);
    unsigned short* Wug2  = (unsigned short*)(wbase + 4 * WBYTES);
    unsigned short* Wb1a  = (unsigned short*)(wbase + 5 * WBYTES);
    unsigned short* Wb1b  = (unsigned short*)(wbase + 6 * WBYTES);
    unsigned short* Wbg1a = (unsigned short*)(wbase + 7 * WBYTES);
    unsigned short* Wbg1b = (unsigned short*)(wbase + 8 * WBYTES);
    unsigned short* Wb2   = (unsigned short*)(wbase + 9 * WBYTES);
    unsigned short* Wbg2  = (unsigned short*)(wbase + 10 * WBYTES);

    // --- prep: weights repack + Xpad build (one launch) ---
    WPrepBatch wb;
    wb.w[0]  = { w_map, Wmap,  33,  0, 33 };
    wb.w[1]  = { w_u1,  Wu1,   64,  0, 64 };
    wb.w[2]  = { w_u2,  Wu2,   64,  0, 64 };
    wb.w[3]  = { w_ug1, Wug1,  64,  0, 64 };
    wb.w[4]  = { w_ug2, Wug2,  64,  0, 64 };
    wb.w[5]  = { w_b1,  Wb1a, 128,  0, 64 };
    wb.w[6]  = { w_b1,  Wb1b, 128, 64, 64 };
    wb.w[7]  = { w_bg1, Wbg1a,128,  0, 64 };
    wb.w[8]  = { w_bg1, Wbg1b,128, 64, 64 };
    wb.w[9]  = { w_b2,  Wb2,   64,  0, 64 };
    wb.w[10] = { w_bg2, Wbg2,  64,  0, 64 };
    prep_k<<<dim3(1584 + 2560), dim3(256), 0, stream>>>(wb, x, t, Xpad);

    // --- map conv: h = conv(Xpad, w_map) + b_map ---
    ConvBatch cm{};
    cm.d[0] = { (const uint4*)Xpad, (const uint4*)Wmap, b_map, h, 0 };
    for (int i = 1; i < 6; ++i) cm.d[i] = cm.d[0];
    conv_mfma_k<<<dim3(NIMG, 1, 2), dim3(256), 0, stream>>>(cm);

    // --- stage 1: six convs from h ---
    ConvBatch c1{};
    c1.d[0] = { (const uint4*)h, (const uint4*)Wu1,   b_u1,  p1,    1 };
    c1.d[1] = { (const uint4*)h, (const uint4*)Wug1,  b_ug1, pg1,   1 };
    c1.d[2] = { (const uint4*)h, (const uint4*)Wb1a,  b_b1,  Abuf,  0 };
    c1.d[3] = { (const uint4*)h, (const uint4*)Wb1b,  nullptr, Bbuf, 0 };
    c1.d[4] = { (const uint4*)h, (const uint4*)Wbg1a, b_bg1, Agbuf, 0 };
    c1.d[5] = { (const uint4*)h, (const uint4*)Wbg1b, nullptr, Bgbuf, 0 };
    conv_mfma_k<<<dim3(NIMG, 6, 2), dim3(256), 0, stream>>>(c1);

    // --- stage 2: u_lin, ug_lin (must finish BEFORE pair overwrites p1/pg1) ---
    ConvBatch c2{};
    c2.d[0] = { (const uint4*)p1,  (const uint4*)Wu2,  b_u2,  u_lin,  0 };
    c2.d[1] = { (const uint4*)pg1, (const uint4*)Wug2, b_ug2, ug_lin, 0 };
    for (int i = 2; i < 6; ++i) c2.d[i] = c2.d[0];
    conv_mfma_k<<<dim3(NIMG, 2, 2), dim3(256), 0, stream>>>(c2);

    // --- pairwise messages -> bf16 partial slabs ---
    pair_mfma_k<<<dim3(400), dim3(512), 0, stream>>>(
        (const uint4*)Abuf, (const uint4*)Bbuf, (const uint4*)Agbuf, (const uint4*)Bgbuf,
        (const uint4*)Wb2, (const uint4*)Wbg2, b_b2, b_bg2, partials);

    // --- final combine ---
    final_k<<<dim3(NIMG), dim3(512), 0, stream>>>(u_lin, ug_lin, partials, out);
}